// Round 1
// baseline (1248.121 us; speedup 1.0000x reference)
//
#include <hip/hip_runtime.h>
#include <math.h>

// ContrastiveLoss (NT-Xent / SimCLR), B=2048, D=1024, tau=0.5.
// loss = (1/n) sum_i [ logsumexp_{j != i}(sim[i,j]/tau) - sim[i,partner]/tau ]
// sim[i,j] = (z_i . z_j) * inv_i * inv_j  with inv = 1/max(||z||, eps)
// z = concat(z_augment, z_orig)  (NOTE: z_augment FIRST per reference)

#define BB   2048
#define N2   4096
#define DIM  1024
#define TAUI 2.0f      // 1/tau
#define EPSN 1e-8f

#define TM 64
#define TN 64
#define BK 64
#define NJ 8
#define JCHUNK (N2 / NJ)   // 512
#define LDP (BK + 4)       // 68 floats: 16B-aligned rows, good bank spread

__device__ __forceinline__ const float* zrow(const float* zO, const float* zA, int r) {
    return (r < BB) ? (zA + (size_t)r * DIM) : (zO + (size_t)(r - BB) * DIM);
}

// ---------------- kernel 1: inverse norms ----------------
__global__ __launch_bounds__(256) void k_norm(const float* __restrict__ zO,
                                              const float* __restrict__ zA,
                                              float* __restrict__ inv_norm) {
    int row = blockIdx.x;
    const float* zr = zrow(zO, zA, row);
    int t = threadIdx.x;
    float4 v = *(const float4*)(zr + t * 4);
    float s = v.x * v.x + v.y * v.y + v.z * v.z + v.w * v.w;
    for (int m = 1; m < 64; m <<= 1) s += __shfl_xor(s, m);
    __shared__ float wsum[4];
    int wave = t >> 6, lane = t & 63;
    if (lane == 0) wsum[wave] = s;
    __syncthreads();
    if (t == 0) {
        float tot = wsum[0] + wsum[1] + wsum[2] + wsum[3];
        inv_norm[row] = 1.0f / fmaxf(sqrtf(tot), EPSN);
    }
}

// ---------------- kernel 2: positive-pair logits ----------------
__global__ __launch_bounds__(256) void k_pos(const float* __restrict__ zO,
                                             const float* __restrict__ zA,
                                             const float* __restrict__ inv_norm,
                                             float* __restrict__ pos) {
    int row = blockIdx.x;
    int p = (row + BB) & (N2 - 1);
    const float* a = zrow(zO, zA, row);
    const float* b = zrow(zO, zA, p);
    int t = threadIdx.x;
    float4 va = *(const float4*)(a + t * 4);
    float4 vb = *(const float4*)(b + t * 4);
    float s = va.x * vb.x + va.y * vb.y + va.z * vb.z + va.w * vb.w;
    for (int m = 1; m < 64; m <<= 1) s += __shfl_xor(s, m);
    __shared__ float wsum[4];
    int wave = t >> 6, lane = t & 63;
    if (lane == 0) wsum[wave] = s;
    __syncthreads();
    if (t == 0) {
        float tot = wsum[0] + wsum[1] + wsum[2] + wsum[3];
        pos[row] = tot * inv_norm[row] * inv_norm[p] * TAUI;
    }
}

// ---------------- kernel 3: fused tile-GEMM + online logsumexp partials ----------------
// grid: (N2/TM, NJ). Each block: 64 rows x one 512-col j-chunk, K=1024.
// Thread grid 16x16: tx covers cols {tx, tx+16, tx+32, tx+48}, ty covers rows ty*4..ty*4+3.
__global__ __launch_bounds__(256) void k_lse(const float* __restrict__ zO,
                                             const float* __restrict__ zA,
                                             const float* __restrict__ inv_norm,
                                             float* __restrict__ pm,
                                             float* __restrict__ pl) {
    __shared__ float As[TM][LDP];
    __shared__ float Bs[TN][LDP];

    int itile = blockIdx.x;
    int chunk = blockIdx.y;
    int ibase = itile * TM;
    int tid = threadIdx.x;
    int tx = tid & 15, ty = tid >> 4;

    const float* Ai = (ibase < BB) ? (zA + (size_t)ibase * DIM)
                                   : (zO + (size_t)(ibase - BB) * DIM);

    float inv_i[4];
#pragma unroll
    for (int q = 0; q < 4; q++) inv_i[q] = inv_norm[ibase + ty * 4 + q];

    float m[4], l[4];
#pragma unroll
    for (int q = 0; q < 4; q++) { m[q] = -1e30f; l[q] = 0.0f; }

    for (int jt = 0; jt < JCHUNK / TN; jt++) {
        int jbase = chunk * JCHUNK + jt * TN;
        const float* Bj = (jbase < BB) ? (zA + (size_t)jbase * DIM)
                                       : (zO + (size_t)(jbase - BB) * DIM);

        float acc[4][4];
#pragma unroll
        for (int q = 0; q < 4; q++)
#pragma unroll
            for (int c = 0; c < 4; c++) acc[q][c] = 0.0f;

        for (int kt = 0; kt < DIM; kt += BK) {
            __syncthreads();
            // stage 64x64 of A and B: 1024 float4 each, 256 threads -> 4 iters
#pragma unroll
            for (int it = 0; it < 4; it++) {
                int idx = it * 256 + tid;      // 0..1023
                int r = idx >> 4;              // 0..63
                int kv = idx & 15;             // 0..15  (float4 index)
                *(float4*)&As[r][kv * 4] = *(const float4*)(Ai + (size_t)r * DIM + kt + kv * 4);
                *(float4*)&Bs[r][kv * 4] = *(const float4*)(Bj + (size_t)r * DIM + kt + kv * 4);
            }
            __syncthreads();

#pragma unroll
            for (int k = 0; k < BK; k += 4) {
                float4 a[4], b[4];
#pragma unroll
                for (int q = 0; q < 4; q++) a[q] = *(const float4*)&As[ty * 4 + q][k];
#pragma unroll
                for (int c = 0; c < 4; c++) b[c] = *(const float4*)&Bs[tx + 16 * c][k];
#pragma unroll
                for (int q = 0; q < 4; q++)
#pragma unroll
                    for (int c = 0; c < 4; c++)
                        acc[q][c] += a[q].x * b[c].x + a[q].y * b[c].y +
                                     a[q].z * b[c].z + a[q].w * b[c].w;
            }
        }

        // epilogue: scale, mask diagonal, online (m,l) update per row
        float inv_j[4];
#pragma unroll
        for (int c = 0; c < 4; c++) inv_j[c] = inv_norm[jbase + tx + 16 * c];

#pragma unroll
        for (int q = 0; q < 4; q++) {
            int ig = ibase + ty * 4 + q;
            float v[4];
            float vmax = -1e30f;
#pragma unroll
            for (int c = 0; c < 4; c++) {
                int jg = jbase + tx + 16 * c;
                float val = acc[q][c] * inv_i[q] * inv_j[c] * TAUI;
                if (jg == ig) val = -1e30f;   // exclude diagonal
                v[c] = val;
                vmax = fmaxf(vmax, val);
            }
#pragma unroll
            for (int mk = 1; mk < 16; mk <<= 1) vmax = fmaxf(vmax, __shfl_xor(vmax, mk));
            float nm = fmaxf(m[q], vmax);
            float s = 0.0f;
#pragma unroll
            for (int c = 0; c < 4; c++) s += __expf(v[c] - nm);
#pragma unroll
            for (int mk = 1; mk < 16; mk <<= 1) s += __shfl_xor(s, mk);
            l[q] = l[q] * __expf(m[q] - nm) + s;
            m[q] = nm;
        }
    }

    if (tx == 0) {
#pragma unroll
        for (int q = 0; q < 4; q++) {
            int ig = ibase + ty * 4 + q;
            pm[chunk * N2 + ig] = m[q];
            pl[chunk * N2 + ig] = l[q];
        }
    }
}

// ---------------- kernel 4: combine partials, final loss ----------------
__global__ __launch_bounds__(256) void k_combine(const float* __restrict__ pm,
                                                 const float* __restrict__ pl,
                                                 const float* __restrict__ pos,
                                                 float* __restrict__ out) {
    int t = threadIdx.x;
    float acc = 0.0f;
    for (int r = t; r < N2; r += 256) {
        float M = -1e30f;
#pragma unroll
        for (int c = 0; c < NJ; c++) M = fmaxf(M, pm[c * N2 + r]);
        float S = 0.0f;
#pragma unroll
        for (int c = 0; c < NJ; c++) S += pl[c * N2 + r] * __expf(pm[c * N2 + r] - M);
        float lse = M + __logf(S);
        acc += lse - pos[r];
    }
    for (int mk = 1; mk < 64; mk <<= 1) acc += __shfl_xor(acc, mk);
    __shared__ float wsum[4];
    int wave = t >> 6, lane = t & 63;
    if (lane == 0) wsum[wave] = acc;
    __syncthreads();
    if (t == 0) out[0] = (wsum[0] + wsum[1] + wsum[2] + wsum[3]) / (float)N2;
}

extern "C" void kernel_launch(void* const* d_in, const int* in_sizes, int n_in,
                              void* d_out, int out_size, void* d_ws, size_t ws_size,
                              hipStream_t stream) {
    const float* zO = (const float*)d_in[0];   // z_orig   -> rows B..2B-1
    const float* zA = (const float*)d_in[1];   // z_augment-> rows 0..B-1
    float* out = (float*)d_out;

    float* inv_norm = (float*)d_ws;            // N2
    float* pos      = inv_norm + N2;           // N2
    float* pm       = pos + N2;                // NJ*N2
    float* pl       = pm + NJ * N2;            // NJ*N2

    k_norm<<<N2, 256, 0, stream>>>(zO, zA, inv_norm);
    k_pos<<<N2, 256, 0, stream>>>(zO, zA, inv_norm, pos);
    k_lse<<<dim3(N2 / TM, NJ), 256, 0, stream>>>(zO, zA, inv_norm, pm, pl);
    k_combine<<<1, 256, 0, stream>>>(pm, pl, pos, out);
}

// Round 7
// 147.491 us; speedup vs baseline: 8.4623x; 8.4623x over previous
//
#include <hip/hip_runtime.h>
#include <hip/hip_bf16.h>
#include <math.h>

// ContrastiveLoss (NT-Xent), B=2048, D=1024, tau=0.5.
// loss = (1/n) sum_i [ logsumexp_{j!=i}(sim[i,j]/tau) - sim[i,partner]/tau ]
// zn = normalize(concat(z_augment, z_orig)) rows; sim = zn @ zn^T (symmetric).
// Strategy: normalize+cast to bf16 once, then MFMA GEMM (m97 structure) with
// fused online-LSE epilogue per 128x128 tile; partner logit extracted in-tile.
// R5 fix: per-wave-column partial slots (jtile*2+wc) — both half-tile waves
// were racing on one pm/pl slot, dropping half the negatives (err ~= log 2).

#define BB   2048
#define N2   4096
#define DIM  1024
#define TAUI 2.0f
#define EPSN 1e-8f

#define BM  128
#define BN  128
#define BKK 64
#define NP  ((N2 / BN) * 2)   // 64 partial slots per row (2 col-half waves/tile)

typedef __attribute__((ext_vector_type(4))) float f32x4;
typedef __attribute__((ext_vector_type(8))) short s16x8;

__device__ __forceinline__ void gll16(const void* g, void* l) {
    __builtin_amdgcn_global_load_lds(
        (const __attribute__((address_space(1))) void*)g,
        (__attribute__((address_space(3))) void*)l, 16, 0, 0);
}

// ------------- kernel 1: row norms + normalized bf16 cast -------------
__global__ __launch_bounds__(256) void k_prep(const float* __restrict__ zO,
                                              const float* __restrict__ zA,
                                              __hip_bfloat16* __restrict__ zb) {
    int row = blockIdx.x;
    const float* zr = (row < BB) ? (zA + (size_t)row * DIM)
                                 : (zO + (size_t)(row - BB) * DIM);
    int t = threadIdx.x;
    float4 v = *(const float4*)(zr + t * 4);
    float s = v.x * v.x + v.y * v.y + v.z * v.z + v.w * v.w;
    for (int m = 1; m < 64; m <<= 1) s += __shfl_xor(s, m);
    __shared__ float wsum[4];
    __shared__ float inv_s;
    int wv = t >> 6, ln = t & 63;
    if (ln == 0) wsum[wv] = s;
    __syncthreads();
    if (t == 0)
        inv_s = 1.0f / fmaxf(sqrtf(wsum[0] + wsum[1] + wsum[2] + wsum[3]), EPSN);
    __syncthreads();
    float inv = inv_s;
    __hip_bfloat16 h0 = __float2bfloat16(v.x * inv);
    __hip_bfloat16 h1 = __float2bfloat16(v.y * inv);
    __hip_bfloat16 h2 = __float2bfloat16(v.z * inv);
    __hip_bfloat16 h3 = __float2bfloat16(v.w * inv);
    ushort4 o;
    o.x = *(unsigned short*)&h0;
    o.y = *(unsigned short*)&h1;
    o.z = *(unsigned short*)&h2;
    o.w = *(unsigned short*)&h3;
    ((ushort4*)zb)[(size_t)row * (DIM / 4) + t] = o;
}

// ------------- kernel 2: MFMA GEMM + fused tile LSE partials -------------
// grid (32,32): block = one 128x128 tile of sim. 4 waves in 2x2; each wave a
// 64x64 sub-tile = 4x4 frags of 16x16x32 bf16 MFMA. BK=64, global_load_lds.
__global__ __launch_bounds__(256) void k_lse(const __hip_bfloat16* __restrict__ zb,
                                             float* __restrict__ pm,
                                             float* __restrict__ pl,
                                             float* __restrict__ pos) {
    __shared__ __hip_bfloat16 As[BM * BKK];   // 16 KB, linear (gll dest)
    __shared__ __hip_bfloat16 Bs[BN * BKK];   // 16 KB

    int itile = blockIdx.x, jtile = blockIdx.y;
    int ibase = itile * BM, jbase = jtile * BN;
    int tid = threadIdx.x;
    int w = tid >> 6, l = tid & 63;
    int wr = w >> 1, wc = w & 1;          // 2x2 wave layout
    int rl = l & 15, kg = l >> 4;

    const __hip_bfloat16* Ag = zb + (size_t)ibase * DIM;
    const __hip_bfloat16* Bg = zb + (size_t)jbase * DIM;

    f32x4 acc[4][4];
#pragma unroll
    for (int m = 0; m < 4; m++)
#pragma unroll
        for (int n = 0; n < 4; n++) acc[m][n] = (f32x4){0.f, 0.f, 0.f, 0.f};

    // per-lane source offsets for staging: one gll16 moves 8 rows x 64 cols
    int srow = l >> 3;            // 0..7 within segment
    int scol = (l & 7) * 8;       // bf16 col offset

    for (int kt = 0; kt < DIM; kt += BKK) {
        __syncthreads();
#pragma unroll
        for (int s4 = 0; s4 < 4; s4++) {
            int s = w * 4 + s4;                  // segment 0..15 (8 rows each)
            int grow = 8 * s + srow;
            gll16(Ag + (size_t)grow * DIM + kt + scol, &As[s * 512]);
            gll16(Bg + (size_t)grow * DIM + kt + scol, &Bs[s * 512]);
        }
        __syncthreads();   // compiler drains vmcnt(0) here (m97 structure)

#pragma unroll
        for (int kk = 0; kk < 2; kk++) {
            s16x8 a[4], b[4];
#pragma unroll
            for (int m = 0; m < 4; m++)
                a[m] = *(const s16x8*)&As[(wr * 64 + m * 16 + rl) * BKK + kk * 32 + kg * 8];
#pragma unroll
            for (int n = 0; n < 4; n++)
                b[n] = *(const s16x8*)&Bs[(wc * 64 + n * 16 + rl) * BKK + kk * 32 + kg * 8];
#pragma unroll
            for (int m = 0; m < 4; m++)
#pragma unroll
                for (int n = 0; n < 4; n++)
                    acc[m][n] = __builtin_amdgcn_mfma_f32_16x16x32_bf16(
                        a[m], b[n], acc[m][n], 0, 0, 0);
        }
    }

    // ---- epilogue: logits, diagonal mask, partner extract, rowwise (m,l) ----
    // C/D mapping (m89): col = lane&15, row = (lane>>4)*4 + reg
    int rowbase = ibase + wr * 64;
    int colbase = jbase + wc * 64;
    int slot = jtile * 2 + wc;            // per-wave-column partial slot
#pragma unroll
    for (int m = 0; m < 4; m++) {
#pragma unroll
        for (int r = 0; r < 4; r++) {
            int ig = rowbase + m * 16 + kg * 4 + r;
            int pp = (ig + BB) & (N2 - 1);
            float v[4];
            float rmax = -1e30f;
#pragma unroll
            for (int n = 0; n < 4; n++) {
                int jg = colbase + n * 16 + rl;
                float val = acc[m][n][r] * TAUI;
                if (jg == pp) pos[ig] = val;      // positive-pair logit
                if (jg == ig) val = -1e30f;       // exclude diagonal
                v[n] = val;
                rmax = fmaxf(rmax, val);
            }
#pragma unroll
            for (int mk = 1; mk < 16; mk <<= 1)
                rmax = fmaxf(rmax, __shfl_xor(rmax, mk));
            float ssum = 0.f;
#pragma unroll
            for (int n = 0; n < 4; n++) ssum += __expf(v[n] - rmax);
#pragma unroll
            for (int mk = 1; mk < 16; mk <<= 1) ssum += __shfl_xor(ssum, mk);
            if (rl == 0) {
                pm[slot * N2 + ig] = rmax;
                pl[slot * N2 + ig] = ssum;
            }
        }
    }
}

// ------------- kernel 3: combine partials -> loss -------------
__global__ __launch_bounds__(128) void k_combine(const float* __restrict__ pm,
                                                 const float* __restrict__ pl,
                                                 const float* __restrict__ pos,
                                                 float* __restrict__ out) {
    int row = blockIdx.x * 128 + threadIdx.x;
    float M = -1e30f;
#pragma unroll
    for (int c = 0; c < NP; c++) M = fmaxf(M, pm[c * N2 + row]);
    float S = 0.f;
#pragma unroll
    for (int c = 0; c < NP; c++) S += pl[c * N2 + row] * __expf(pm[c * N2 + row] - M);
    float v = M + __logf(S) - pos[row];
    for (int mk = 1; mk < 64; mk <<= 1) v += __shfl_xor(v, mk);
    __shared__ float w0;
    if (threadIdx.x == 0) w0 = v;
    __syncthreads();
    if (threadIdx.x == 64) atomicAdd(out, (v + w0) * (1.0f / (float)N2));
}

extern "C" void kernel_launch(void* const* d_in, const int* in_sizes, int n_in,
                              void* d_out, int out_size, void* d_ws, size_t ws_size,
                              hipStream_t stream) {
    const float* zO = (const float*)d_in[0];   // z_orig    -> rows B..2B-1
    const float* zA = (const float*)d_in[1];   // z_augment -> rows 0..B-1
    float* out = (float*)d_out;

    __hip_bfloat16* zb = (__hip_bfloat16*)d_ws;          // 4096*1024 bf16 = 8 MB
    float* pm  = (float*)((char*)d_ws + (size_t)N2 * DIM * 2);   // 64*4096
    float* pl  = pm + NP * N2;                                    // 64*4096
    float* pos = pl + NP * N2;                                    // 4096

    hipMemsetAsync(out, 0, sizeof(float), stream);
    k_prep<<<N2, 256, 0, stream>>>(zO, zA, zb);
    k_lse<<<dim3(N2 / BM, N2 / BN), 256, 0, stream>>>(zb, pm, pl, pos);
    k_combine<<<N2 / 128, 128, 0, stream>>>(pm, pl, pos, out);
}

// Round 9
// 133.784 us; speedup vs baseline: 9.3294x; 1.1025x over previous
//
#include <hip/hip_runtime.h>
#include <hip/hip_bf16.h>
#include <math.h>

// ContrastiveLoss (NT-Xent), B=2048, D=1024, tau=0.5.
// loss = (1/n) sum_i [ logsumexp_{j!=i}(sim[i,j]/tau) - sim[i,partner]/tau ]
// sim = zn @ zn^T is SYMMETRIC: compute only upper-triangle 128x128 tiles
// (528 blocks vs 1024). Off-diagonal tiles emit row-wise partials (for tile
// ti's rows) AND column-wise partials (for tile tj's rows). Slot algebra:
// row-partials use slot=2*tj+wc (>= 2*ti), col-partials slot=2*ti+wr (< 2*tj)
// -> for any output row, all 64 slots written exactly once, race-free.
// R7: symmetry halves GEMM+staging (k_lse was staging-BW bound at ~7.6 TB/s
// L2/L3 rate); pm/pl transposed to [row][slot] for coalesced k_combine.

#define BB   2048
#define N2   4096
#define DIM  1024
#define TAUI 2.0f
#define EPSN 1e-8f

#define BM  128
#define BN  128
#define BKK 64
#define NP  64            // partial slots per row
#define NBLK 528          // 32*33/2 upper-triangle tiles

typedef __attribute__((ext_vector_type(4))) float f32x4;
typedef __attribute__((ext_vector_type(8))) short s16x8;

__device__ __forceinline__ void gll16(const void* g, void* l) {
    __builtin_amdgcn_global_load_lds(
        (const __attribute__((address_space(1))) void*)g,
        (__attribute__((address_space(3))) void*)l, 16, 0, 0);
}

// ------------- kernel 1: row norms + normalized bf16 cast -------------
__global__ __launch_bounds__(256) void k_prep(const float* __restrict__ zO,
                                              const float* __restrict__ zA,
                                              __hip_bfloat16* __restrict__ zb) {
    int row = blockIdx.x;
    const float* zr = (row < BB) ? (zA + (size_t)row * DIM)
                                 : (zO + (size_t)(row - BB) * DIM);
    int t = threadIdx.x;
    float4 v = *(const float4*)(zr + t * 4);
    float s = v.x * v.x + v.y * v.y + v.z * v.z + v.w * v.w;
    for (int m = 1; m < 64; m <<= 1) s += __shfl_xor(s, m);
    __shared__ float wsum[4];
    __shared__ float inv_s;
    int wv = t >> 6, ln = t & 63;
    if (ln == 0) wsum[wv] = s;
    __syncthreads();
    if (t == 0)
        inv_s = 1.0f / fmaxf(sqrtf(wsum[0] + wsum[1] + wsum[2] + wsum[3]), EPSN);
    __syncthreads();
    float inv = inv_s;
    __hip_bfloat16 h0 = __float2bfloat16(v.x * inv);
    __hip_bfloat16 h1 = __float2bfloat16(v.y * inv);
    __hip_bfloat16 h2 = __float2bfloat16(v.z * inv);
    __hip_bfloat16 h3 = __float2bfloat16(v.w * inv);
    ushort4 o;
    o.x = *(unsigned short*)&h0;
    o.y = *(unsigned short*)&h1;
    o.z = *(unsigned short*)&h2;
    o.w = *(unsigned short*)&h3;
    ((ushort4*)zb)[(size_t)row * (DIM / 4) + t] = o;
}

// ------------- kernel 2: MFMA GEMM (upper-triangle) + LSE partials -------------
__global__ __launch_bounds__(256) void k_lse(const __hip_bfloat16* __restrict__ zb,
                                             float* __restrict__ pm,
                                             float* __restrict__ pl,
                                             float* __restrict__ pos) {
    __shared__ __hip_bfloat16 As[BM * BKK];   // 16 KB, linear (gll dest)
    __shared__ __hip_bfloat16 Bs[BN * BKK];   // 16 KB

    // linear block id -> (ti, tj), ti <= tj; offset(t) = t*(65-t)/2
    int lin = blockIdx.x;
    int ti = (int)((65.0f - sqrtf(4225.0f - 8.0f * (float)lin)) * 0.5f);
    while ((ti + 1) * (65 - (ti + 1)) / 2 <= lin) ti++;
    while (ti * (65 - ti) / 2 > lin) ti--;
    int tj = ti + (lin - ti * (65 - ti) / 2);

    int ibase = ti * BM, jbase = tj * BN;
    int tid = threadIdx.x;
    int w = tid >> 6, l = tid & 63;
    int wr = w >> 1, wc = w & 1;          // 2x2 wave layout
    int rl = l & 15, kg = l >> 4;

    const __hip_bfloat16* Ag = zb + (size_t)ibase * DIM;
    const __hip_bfloat16* Bg = zb + (size_t)jbase * DIM;

    f32x4 acc[4][4];
#pragma unroll
    for (int m = 0; m < 4; m++)
#pragma unroll
        for (int n = 0; n < 4; n++) acc[m][n] = (f32x4){0.f, 0.f, 0.f, 0.f};

    int srow = l >> 3;            // 0..7 within segment
    int scol = (l & 7) * 8;       // bf16 col offset

    for (int kt = 0; kt < DIM; kt += BKK) {
        __syncthreads();
#pragma unroll
        for (int s4 = 0; s4 < 4; s4++) {
            int s = w * 4 + s4;                  // segment 0..15 (8 rows each)
            int grow = 8 * s + srow;
            gll16(Ag + (size_t)grow * DIM + kt + scol, &As[s * 512]);
            gll16(Bg + (size_t)grow * DIM + kt + scol, &Bs[s * 512]);
        }
        __syncthreads();

#pragma unroll
        for (int kk = 0; kk < 2; kk++) {
            s16x8 a[4], b[4];
#pragma unroll
            for (int m = 0; m < 4; m++)
                a[m] = *(const s16x8*)&As[(wr * 64 + m * 16 + rl) * BKK + kk * 32 + kg * 8];
#pragma unroll
            for (int n = 0; n < 4; n++)
                b[n] = *(const s16x8*)&Bs[(wc * 64 + n * 16 + rl) * BKK + kk * 32 + kg * 8];
#pragma unroll
            for (int m = 0; m < 4; m++)
#pragma unroll
                for (int n = 0; n < 4; n++)
                    acc[m][n] = __builtin_amdgcn_mfma_f32_16x16x32_bf16(
                        a[m], b[n], acc[m][n], 0, 0, 0);
        }
    }

    // ---- row-path epilogue: per-row (max, sumexp) over this tile's 64 cols ----
    // C/D mapping (m89): col = lane&15, row = (lane>>4)*4 + reg
    int rowbase = ibase + wr * 64;
    int colbase = jbase + wc * 64;
    int slot = tj * 2 + wc;               // row-partial slot
#pragma unroll
    for (int m = 0; m < 4; m++) {
#pragma unroll
        for (int r = 0; r < 4; r++) {
            int ig = rowbase + m * 16 + kg * 4 + r;
            int pp = (ig + BB) & (N2 - 1);
            float v[4];
            float rmax = -1e30f;
#pragma unroll
            for (int n = 0; n < 4; n++) {
                int jg = colbase + n * 16 + rl;
                float val = acc[m][n][r] * TAUI;
                if (jg == pp) { pos[ig] = val; pos[jg] = val; }  // sim symmetric
                if (jg == ig) val = -1e30f;       // exclude diagonal
                v[n] = val;
                rmax = fmaxf(rmax, val);
            }
#pragma unroll
            for (int mk = 1; mk < 16; mk <<= 1)
                rmax = fmaxf(rmax, __shfl_xor(rmax, mk));
            float ssum = 0.f;
#pragma unroll
            for (int n = 0; n < 4; n++) ssum += __expf(v[n] - rmax);
#pragma unroll
            for (int mk = 1; mk < 16; mk <<= 1) ssum += __shfl_xor(ssum, mk);
            if (rl == 0) {
                pm[(size_t)ig * NP + slot] = rmax;
                pl[(size_t)ig * NP + slot] = ssum;
            }
        }
    }

    // ---- col-path epilogue (off-diagonal only): per-col stats = partials
    // for tile tj's rows over tile ti's 64 rows (this wave's wr half) ----
    if (ti != tj) {
        int slot2 = ti * 2 + wr;
#pragma unroll
        for (int n = 0; n < 4; n++) {
            float cmax = -1e30f;
#pragma unroll
            for (int m = 0; m < 4; m++)
#pragma unroll
                for (int r = 0; r < 4; r++)
                    cmax = fmaxf(cmax, acc[m][n][r] * TAUI);
            cmax = fmaxf(cmax, __shfl_xor(cmax, 16));
            cmax = fmaxf(cmax, __shfl_xor(cmax, 32));
            float cs = 0.f;
#pragma unroll
            for (int m = 0; m < 4; m++)
#pragma unroll
                for (int r = 0; r < 4; r++)
                    cs += __expf(acc[m][n][r] * TAUI - cmax);
            cs += __shfl_xor(cs, 16);
            cs += __shfl_xor(cs, 32);
            if (l < 16) {                        // kg==0 lanes
                int jg = colbase + n * 16 + rl;
                pm[(size_t)jg * NP + slot2] = cmax;
                pl[(size_t)jg * NP + slot2] = cs;
            }
        }
    }
}

// ------------- kernel 3: combine partials -> loss -------------
__global__ __launch_bounds__(256) void k_combine(const float* __restrict__ pm,
                                                 const float* __restrict__ pl,
                                                 const float* __restrict__ pos,
                                                 float* __restrict__ out) {
    int row = blockIdx.x * 256 + threadIdx.x;
    const float* P = pm + (size_t)row * NP;    // contiguous 64 floats
    const float* L = pl + (size_t)row * NP;
    float M = -1e30f;
#pragma unroll
    for (int c = 0; c < NP; c++) M = fmaxf(M, P[c]);
    float S = 0.f;
#pragma unroll
    for (int c = 0; c < NP; c++) S += L[c] * __expf(P[c] - M);
    float v = M + __logf(S) - pos[row];
    for (int mk = 1; mk < 64; mk <<= 1) v += __shfl_xor(v, mk);
    __shared__ float wsum[4];
    int wv = threadIdx.x >> 6, ln = threadIdx.x & 63;
    if (ln == 0) wsum[wv] = v;
    __syncthreads();
    if (threadIdx.x == 0)
        atomicAdd(out, (wsum[0] + wsum[1] + wsum[2] + wsum[3]) * (1.0f / (float)N2));
}

extern "C" void kernel_launch(void* const* d_in, const int* in_sizes, int n_in,
                              void* d_out, int out_size, void* d_ws, size_t ws_size,
                              hipStream_t stream) {
    const float* zO = (const float*)d_in[0];   // z_orig    -> rows B..2B-1
    const float* zA = (const float*)d_in[1];   // z_augment -> rows 0..B-1
    float* out = (float*)d_out;

    __hip_bfloat16* zb = (__hip_bfloat16*)d_ws;          // 4096*1024 bf16 = 8 MB
    float* pm  = (float*)((char*)d_ws + (size_t)N2 * DIM * 2);   // [4096][64]
    float* pl  = pm + (size_t)N2 * NP;                            // [4096][64]
    float* pos = pl + (size_t)N2 * NP;                            // 4096

    hipMemsetAsync(out, 0, sizeof(float), stream);
    k_prep<<<N2, 256, 0, stream>>>(zO, zA, zb);
    k_lse<<<NBLK, 256, 0, stream>>>(zb, pm, pl, pos);
    k_combine<<<N2 / 256, 256, 0, stream>>>(pm, pl, pos, out);
}